// Round 3
// baseline (908.480 us; speedup 1.0000x reference)
//
#include <hip/hip_runtime.h>
#include <cstddef>
#include <cstdint>

typedef __attribute__((ext_vector_type(4))) float f32x4;
typedef __attribute__((ext_vector_type(8))) short short8;

#define HID 128
#define NK1 -1.4426950408889634f  // -log2(e)
#define PK2 2.8853900817779268f   // +2*log2(e)

// LDS-only barrier: no vmcnt(0) drain.
#define BAR_LGKM() __asm__ volatile("s_waitcnt lgkmcnt(0)\ns_barrier" ::: "memory")
// depth-2 prefetch fence (4 DMA loads/wave/ts): retire gather(t), keep gather(t+1)
#define STEP_BAR() __asm__ volatile("s_waitcnt vmcnt(4) lgkmcnt(0)\ns_barrier" ::: "memory")

__device__ __forceinline__ short f2bf(float f) {
  unsigned u = __builtin_bit_cast(unsigned, f);
  u += 0x7FFFu + ((u >> 16) & 1u);
  return (short)(u >> 16);
}
__device__ __forceinline__ unsigned pack_bf2(float a, float b) {
  unsigned ua = __builtin_bit_cast(unsigned, a) + 0x8000u;
  unsigned ub = __builtin_bit_cast(unsigned, b) + 0x8000u;
  return __builtin_amdgcn_perm(ub, ua, 0x07060302u);
}
__device__ __forceinline__ float2 unpack2v(int w) {
  float2 r;
  r.x = __builtin_bit_cast(float, (unsigned)(w << 16));
  r.y = __builtin_bit_cast(float, (unsigned)w & 0xffff0000u);
  return r;
}

// folded LSTM cell: inputs are PRE-SCALED pre-activations
// si,sf,so = -log2e*(gate), sg = 2log2e*(g). 5 exp2 + 2 rcp (algebraic min).
__device__ __forceinline__ float lstm_elem(float si, float sf, float sg, float so, float& c) {
  float Ei = __builtin_amdgcn_exp2f(si);
  float Ef = __builtin_amdgcn_exp2f(sf);
  float Tg = __builtin_amdgcn_exp2f(sg);
  float Eo = __builtin_amdgcn_exp2f(so);
  float u = 1.0f + Ei, w = 1.0f + Ef, v = Tg + 1.0f, Tm = Tg - 1.0f;
  float t0 = u * v;
  float num = __builtin_fmaf(c, t0, w * Tm);
  float cn = num * __builtin_amdgcn_rcpf(w * t0);
  c = cn;
  float Tc = __builtin_amdgcn_exp2f(PK2 * cn);
  return (Tc - 1.0f) * __builtin_amdgcn_rcpf((1.0f + Eo) * (Tc + 1.0f));
}

// ---------------- conversion kernels ----------------
__global__ void conv_x_kernel(const float* __restrict__ x, short* __restrict__ xb, int n,
                              int* __restrict__ tctr) {
  int i = blockIdx.x * blockDim.x + threadIdx.x;
  if (i < 8) tctr[i] = 0;  // zero dynamic-tile counters (runs before all lstm dispatches)
  int stride = gridDim.x * blockDim.x;
  for (; i < n; i += stride) xb[i] = f2bf(x[i]);
}

// pre-scales LSTM weights/bias by gate: i,f,o -> -log2e ; g -> +2log2e
__global__ void conv_layer_kernel(const float* __restrict__ Wih, const float* __restrict__ Whh,
                                  const float* __restrict__ bih, const float* __restrict__ bhh,
                                  const float* __restrict__ Wl, const float* __restrict__ Wr, int foK,
                                  short* __restrict__ wihB, short* __restrict__ whhB,
                                  short* __restrict__ wlB, short* __restrict__ wrB,
                                  float* __restrict__ bsum) {
  int i = blockIdx.x * blockDim.x + threadIdx.x;
  if (i < 512 * HID) {
    float sc = ((i >> 14) == 2) ? PK2 : NK1;  // gate = row>>7 = i>>14
    wihB[i] = f2bf(Wih[i] * sc);
    whhB[i] = f2bf(Whh[i] * sc);
  }
  if (i < foK) { wlB[i] = f2bf(Wl[i]); wrB[i] = f2bf(Wr[i]); }
  if (i < 512) bsum[i] = (bih[i] + bhh[i]) * (((i >> 7) == 2) ? PK2 : NK1);
}

// ------- persistent P-GEMM: P = A @ Wih^T + bias -> bf16 [M,512] -------------
#define OSTR 524
__global__ __launch_bounds__(512, 4) void pgemm_kernel(
    const short* __restrict__ A, const short* __restrict__ W,
    const float* __restrict__ bias, short* __restrict__ out, int M, int ntiles) {
  __shared__ short ldsO[32 * OSTR];  // 33.5 KB
  const int tid = threadIdx.x;
  const int wave = tid >> 6, lane = tid & 63;
  const int quad = lane >> 4, nn = lane & 15;
  const int cbase = wave * 64;

  short8 wreg[4][4];
#pragma unroll
  for (int kt = 0; kt < 4; ++kt)
#pragma unroll
    for (int nt = 0; nt < 4; ++nt)
      wreg[kt][nt] = *(const short8*)(W + (size_t)(cbase + nt * 16 + nn) * HID + kt * 32 + quad * 8);
  f32x4 bias4[4];
#pragma unroll
  for (int nt = 0; nt < 4; ++nt)
#pragma unroll
    for (int r = 0; r < 4; ++r) bias4[nt][r] = bias[cbase + nt * 16 + quad * 4 + r];

#pragma unroll 1
  for (int rt = blockIdx.x; rt < ntiles; rt += gridDim.x) {
    const int row0 = rt * 32;
    f32x4 acc[2][4];
#pragma unroll
    for (int b = 0; b < 2; ++b)
#pragma unroll
      for (int nt = 0; nt < 4; ++nt) acc[b][nt] = bias4[nt];
#pragma unroll
    for (int kt = 0; kt < 4; ++kt) {
      int r0 = row0 + nn;      if (r0 > M - 1) r0 = M - 1;
      int r1 = row0 + 16 + nn; if (r1 > M - 1) r1 = M - 1;
      short8 af0 = *(const short8*)(A + (size_t)r0 * HID + kt * 32 + quad * 8);
      short8 af1 = *(const short8*)(A + (size_t)r1 * HID + kt * 32 + quad * 8);
#pragma unroll
      for (int nt = 0; nt < 4; ++nt) {
        acc[0][nt] = __builtin_amdgcn_mfma_f32_16x16x32_bf16(wreg[kt][nt], af0, acc[0][nt], 0, 0, 0);
        acc[1][nt] = __builtin_amdgcn_mfma_f32_16x16x32_bf16(wreg[kt][nt], af1, acc[1][nt], 0, 0, 0);
      }
    }
    BAR_LGKM();  // previous iteration's ldsO reads complete
#pragma unroll
    for (int b = 0; b < 2; ++b)
#pragma unroll
      for (int nt = 0; nt < 4; ++nt) {
        uint2 pk;
        pk.x = pack_bf2(acc[b][nt][0], acc[b][nt][1]);
        pk.y = pack_bf2(acc[b][nt][2], acc[b][nt][3]);
        *(uint2*)(ldsO + (b * 16 + nn) * OSTR + cbase + nt * 16 + quad * 4) = pk;
      }
    BAR_LGKM();
#pragma unroll
    for (int idx = tid; idx < 32 * 64; idx += 512) {
      int row = idx >> 6, c8 = (idx & 63) * 8;
      if (row0 + row < M)
        *(short8*)(out + (size_t)(row0 + row) * 512 + c8) = *(const short8*)(ldsO + row * OSTR + c8);
    }
  }
}

// ------- persistent LSTM + FUSED output GEMM ---------------------------------
// v4: NPB=32 — TWO independent 16-node recurrence chains per barrier interval
//     (dual acc/cell sets per wave) so the serial h-chain latency of one half
//     hides under the issue work of the other. 1 block/CU (121 KB LDS),
//     depth-2 DMA prefetch, dynamic tile scheduling.
#define NPB 32
#define PSTR 520
#define HSTR 152
#define NPBUF 3
#define LSTM_LDS_BYTES ((NPBUF * NPB * PSTR + 2 * NPB * HSTR) * 2 + 512 * 4 + 16)  // 121360

template <int FO, bool RELU, bool OUTF32>
__global__ __launch_bounds__(512, 2) void lstm_fused_kernel(
    const short* __restrict__ P, const short* __restrict__ Whh,
    const int* __restrict__ src, const short* __restrict__ cur,
    const short* __restrict__ Wl, const short* __restrict__ Wr,
    const float* __restrict__ bl,
    short* __restrict__ outB, float* __restrict__ outF, int M, int ntiles,
    int* __restrict__ tctr) {
  extern __shared__ char smem[];
  short* Pb = (short*)smem;                     // [3][32][520]
  short* Hb = Pb + NPBUF * NPB * PSTR;          // [2][32][152]
  int* srcL = (int*)(Hb + 2 * NPB * HSTR);      // [512] = [node 0..31][t 0..15]
  int* nextTp = srcL + 512;

  const int tid = threadIdx.x;
  const int wave = tid >> 6, lane = tid & 63;
  const int quad = lane >> 4, nn = lane & 15;
  const int grow = wave * 4;  // this wave's 4 gather rows

  // Whh fragments: for each gate q, rows [q*128 + wave*16, +16)  (64 VGPRs)
  short8 wreg[4][4];  // [kt][q]
#pragma unroll
  for (int kt = 0; kt < 4; ++kt)
#pragma unroll
    for (int q = 0; q < 4; ++q)
      wreg[kt][q] = *(const short8*)(Whh + (size_t)(q * 128 + wave * 16 + nn) * HID + kt * 32 + quad * 8);

  // epilogue weights + bias, register-resident
  const int ecol = (FO == 128) ? wave * 16 : (wave & 3) * 16;
  f32x4 biasO;
  short8 wlR[4], wrR[4];
#pragma unroll
  for (int r = 0; r < 4; ++r) biasO[r] = bl[ecol + quad * 4 + r];
#pragma unroll
  for (int kt = 0; kt < 4; ++kt) {
    wlR[kt] = *(const short8*)(Wl + (size_t)(ecol + nn) * HID + kt * 32 + quad * 8);
    wrR[kt] = *(const short8*)(Wr + (size_t)(ecol + nn) * HID + kt * 32 + quad * 8);
  }

  int tile = blockIdx.x;
  while (tile < ntiles) {
    const int nodeBase = tile * NPB;
    {
      int node = nodeBase + (tid >> 4);
      srcL[tid] = (node < M) ? src[nodeBase * 16 + tid] : 0;
    }
    if (tid == 0) *nextTp = (int)gridDim.x + atomicAdd(tctr, 1);
    float c0[4] = {0.f, 0.f, 0.f, 0.f};
    float c1[4] = {0.f, 0.f, 0.f, 0.f};
    BAR_LGKM();  // srcL + nextT visible; prev tile's LDS reads done
    const int my_next = *nextTp;  // read post-barrier; next write is >16 barriers away

    // prologue: gather(0) -> buf0, gather(1) -> buf1  (4 rows per wave each)
#pragma unroll
    for (int tt = 0; tt < 2; ++tt) {
#pragma unroll
      for (int j = 0; j < 4; ++j) {
        int s = srcL[(grow + j) * 16 + tt];
        __builtin_amdgcn_global_load_lds(
            (const __attribute__((address_space(1))) unsigned int*)(P + (size_t)s * 512 + lane * 8),
            (__attribute__((address_space(3))) unsigned int*)(Pb + tt * NPB * PSTR + (grow + j) * PSTR),
            16, 0, 0);
      }
    }

    int pc = 0, pg = 2;  // buffer of P(t) and of gather target (t+2)
#pragma unroll 1
    for (int t = 0; t < 16; ++t) {
      short* Pc = Pb + pc * NPB * PSTR;
      short* Pg = Pb + pg * NPB * PSTR;
      const short* Hp = Hb + ((t + 1) & 1) * NPB * HSTR;  // h(t-1)
      short* Hw = Hb + (t & 1) * NPB * HSTR;              // h(t)
      pc = (pc == NPBUF - 1) ? 0 : pc + 1;
      pg = (pg == NPBUF - 1) ? 0 : pg + 1;

      STEP_BAR();  // gather(t) landed everywhere; gather(t+1) stays in flight

      // ---- read P-frags for BOTH halves, unpack into acc (MFMA C-operand) ----
      f32x4 acc0[4], acc1[4];
      {
        const short* pR = Pc + nn * PSTR + wave * 16 + quad * 4;
        uint2 q0 = *(const uint2*)(pR + 0 * 128);
        uint2 q1 = *(const uint2*)(pR + 1 * 128);
        uint2 q2 = *(const uint2*)(pR + 2 * 128);
        uint2 q3 = *(const uint2*)(pR + 3 * 128);
        float2 u, v;
        u = unpack2v(q0.x); v = unpack2v(q0.y);
        acc0[0][0] = u.x; acc0[0][1] = u.y; acc0[0][2] = v.x; acc0[0][3] = v.y;
        u = unpack2v(q1.x); v = unpack2v(q1.y);
        acc0[1][0] = u.x; acc0[1][1] = u.y; acc0[1][2] = v.x; acc0[1][3] = v.y;
        u = unpack2v(q2.x); v = unpack2v(q2.y);
        acc0[2][0] = u.x; acc0[2][1] = u.y; acc0[2][2] = v.x; acc0[2][3] = v.y;
        u = unpack2v(q3.x); v = unpack2v(q3.y);
        acc0[3][0] = u.x; acc0[3][1] = u.y; acc0[3][2] = v.x; acc0[3][3] = v.y;
      }
      {
        const short* pR = Pc + (16 + nn) * PSTR + wave * 16 + quad * 4;
        uint2 q0 = *(const uint2*)(pR + 0 * 128);
        uint2 q1 = *(const uint2*)(pR + 1 * 128);
        uint2 q2 = *(const uint2*)(pR + 2 * 128);
        uint2 q3 = *(const uint2*)(pR + 3 * 128);
        float2 u, v;
        u = unpack2v(q0.x); v = unpack2v(q0.y);
        acc1[0][0] = u.x; acc1[0][1] = u.y; acc1[0][2] = v.x; acc1[0][3] = v.y;
        u = unpack2v(q1.x); v = unpack2v(q1.y);
        acc1[1][0] = u.x; acc1[1][1] = u.y; acc1[1][2] = v.x; acc1[1][3] = v.y;
        u = unpack2v(q2.x); v = unpack2v(q2.y);
        acc1[2][0] = u.x; acc1[2][1] = u.y; acc1[2][2] = v.x; acc1[2][3] = v.y;
        u = unpack2v(q3.x); v = unpack2v(q3.y);
        acc1[3][0] = u.x; acc1[3][1] = u.y; acc1[3][2] = v.x; acc1[3][3] = v.y;
      }

      // ---- issue gather(t+2) (clamped dummy at t>=14 keeps vmcnt uniform) ----
      {
        int tn = (t + 2 < 16) ? t + 2 : 15;
#pragma unroll
        for (int j = 0; j < 4; ++j) {
          int s = srcL[(grow + j) * 16 + tn];
          __builtin_amdgcn_global_load_lds(
              (const __attribute__((address_space(1))) unsigned int*)(P + (size_t)s * 512 + lane * 8),
              (__attribute__((address_space(3))) unsigned int*)(Pg + (grow + j) * PSTR), 16, 0, 0);
        }
      }

      // ---- acc += Whh_rows @ h(t-1)^T  (both halves, interleaved) ----
      if (t) {
#pragma unroll
        for (int kt = 0; kt < 4; ++kt) {
          short8 hb0 = *(const short8*)(Hp + nn * HSTR + kt * 32 + quad * 8);
          short8 hb1 = *(const short8*)(Hp + (16 + nn) * HSTR + kt * 32 + quad * 8);
#pragma unroll
          for (int q = 0; q < 4; ++q) {
            acc0[q] = __builtin_amdgcn_mfma_f32_16x16x32_bf16(wreg[kt][q], hb0, acc0[q], 0, 0, 0);
            acc1[q] = __builtin_amdgcn_mfma_f32_16x16x32_bf16(wreg[kt][q], hb1, acc1[q], 0, 0, 0);
          }
        }
      }

      // ---- cells: two independent chains, write h(t) for both halves ----
      float hv0[4], hv1[4];
#pragma unroll
      for (int r = 0; r < 4; ++r)
        hv0[r] = lstm_elem(acc0[0][r], acc0[1][r], acc0[2][r], acc0[3][r], c0[r]);
#pragma unroll
      for (int r = 0; r < 4; ++r)
        hv1[r] = lstm_elem(acc1[0][r], acc1[1][r], acc1[2][r], acc1[3][r], c1[r]);
      uint2 pk0, pk1;
      pk0.x = pack_bf2(hv0[0], hv0[1]);
      pk0.y = pack_bf2(hv0[2], hv0[3]);
      pk1.x = pack_bf2(hv1[0], hv1[1]);
      pk1.y = pack_bf2(hv1[2], hv1[3]);
      *(uint2*)(Hw + nn * HSTR + wave * 16 + quad * 4) = pk0;
      *(uint2*)(Hw + (16 + nn) * HSTR + wave * 16 + quad * 4) = pk1;
    }

    BAR_LGKM();  // h(15) visible (buf1)

    // ---- FUSED output: out[node] = h15@Wl^T + bl + cur@Wr^T ----
    {
      const short* Hf = Hb + NPB * HSTR;
      if (FO == 128) {
        f32x4 accO0 = biasO, accO1 = biasO;
#pragma unroll
        for (int kt = 0; kt < 4; ++kt) {
          short8 hb0 = *(const short8*)(Hf + nn * HSTR + kt * 32 + quad * 8);
          short8 hb1 = *(const short8*)(Hf + (16 + nn) * HSTR + kt * 32 + quad * 8);
          accO0 = __builtin_amdgcn_mfma_f32_16x16x32_bf16(wlR[kt], hb0, accO0, 0, 0, 0);
          accO1 = __builtin_amdgcn_mfma_f32_16x16x32_bf16(wlR[kt], hb1, accO1, 0, 0, 0);
          short8 cb0 = *(const short8*)(cur + (size_t)(nodeBase + nn) * HID + kt * 32 + quad * 8);
          short8 cb1 = *(const short8*)(cur + (size_t)(nodeBase + 16 + nn) * HID + kt * 32 + quad * 8);
          accO0 = __builtin_amdgcn_mfma_f32_16x16x32_bf16(wrR[kt], cb0, accO0, 0, 0, 0);
          accO1 = __builtin_amdgcn_mfma_f32_16x16x32_bf16(wrR[kt], cb1, accO1, 0, 0, 0);
        }
        if (RELU) {
#pragma unroll
          for (int r = 0; r < 4; ++r) {
            accO0[r] = fmaxf(accO0[r], 0.0f);
            accO1[r] = fmaxf(accO1[r], 0.0f);
          }
        }
        int node0 = nodeBase + nn, node1 = nodeBase + 16 + nn;
        if (node0 < M) {
          uint2 pko;
          pko.x = pack_bf2(accO0[0], accO0[1]);
          pko.y = pack_bf2(accO0[2], accO0[3]);
          *(uint2*)(outB + (size_t)node0 * FO + ecol + quad * 4) = pko;
        }
        if (node1 < M) {
          uint2 pko;
          pko.x = pack_bf2(accO1[0], accO1[1]);
          pko.y = pack_bf2(accO1[2], accO1[3]);
          *(uint2*)(outB + (size_t)node1 * FO + ecol + quad * 4) = pko;
        }
      } else {
        const int half = wave >> 2;
        f32x4 accO = biasO;
#pragma unroll
        for (int kt = 0; kt < 4; ++kt) {
          short8 hb = *(const short8*)(Hf + (half * 16 + nn) * HSTR + kt * 32 + quad * 8);
          accO = __builtin_amdgcn_mfma_f32_16x16x32_bf16(wlR[kt], hb, accO, 0, 0, 0);
          short8 cb = *(const short8*)(cur + (size_t)(nodeBase + half * 16 + nn) * HID + kt * 32 + quad * 8);
          accO = __builtin_amdgcn_mfma_f32_16x16x32_bf16(wrR[kt], cb, accO, 0, 0, 0);
        }
        int node = nodeBase + half * 16 + nn;
        if (node < M)
          *(f32x4*)(outF + (size_t)node * FO + ecol + quad * 4) = accO;
      }
    }
    tile = my_next;
  }
}

// ---------------- launcher ----------------
extern "C" void kernel_launch(void* const* d_in, const int* in_sizes, int n_in,
                              void* d_out, int out_size, void* d_ws, size_t ws_size,
                              hipStream_t stream) {
  const float* x = (const float*)d_in[0];
  const int* src = (const int*)d_in[1];
  const float* Wih[3] = {(const float*)d_in[2], (const float*)d_in[9], (const float*)d_in[16]};
  const float* Whh[3] = {(const float*)d_in[3], (const float*)d_in[10], (const float*)d_in[17]};
  const float* bih[3] = {(const float*)d_in[4], (const float*)d_in[11], (const float*)d_in[18]};
  const float* bhh[3] = {(const float*)d_in[5], (const float*)d_in[12], (const float*)d_in[19]};
  const float* Wl[3]  = {(const float*)d_in[6], (const float*)d_in[13], (const float*)d_in[20]};
  const float* bl[3]  = {(const float*)d_in[7], (const float*)d_in[14], (const float*)d_in[21]};
  const float* Wr[3]  = {(const float*)d_in[8], (const float*)d_in[15], (const float*)d_in[22]};

  const int M = in_sizes[0] / HID;  // 50000

  char* ws = (char*)d_ws;
  size_t off = 0;
  auto alloc = [&](size_t bytes) -> void* {
    void* p = ws + off;
    off += (bytes + 255) & ~(size_t)255;
    return p;
  };
  short* curA = (short*)alloc((size_t)M * HID * 2);
  short* curB = (short*)alloc((size_t)M * HID * 2);
  short* Pbuf = (short*)alloc((size_t)M * 512 * 2);
  short* wihB[3]; short* whhB[3]; short* wlB[3]; short* wrB[3]; float* bsum[3];
  for (int l = 0; l < 3; ++l) {
    wihB[l] = (short*)alloc(512 * HID * 2);
    whhB[l] = (short*)alloc(512 * HID * 2);
    wlB[l]  = (short*)alloc(HID * HID * 2);
    wrB[l]  = (short*)alloc(HID * HID * 2);
    bsum[l] = (float*)alloc(512 * 4);
  }
  int* tctr = (int*)alloc(256);  // dynamic-tile counters (zeroed by conv_x_kernel)

  const int nltiles = (M + NPB - 1) / NPB;  // 1563
  const int ntiles = (M + 31) / 32;         // 1563

  (void)hipFuncSetAttribute((const void*)lstm_fused_kernel<128, true, false>,
                            hipFuncAttributeMaxDynamicSharedMemorySize, LSTM_LDS_BYTES);
  (void)hipFuncSetAttribute((const void*)lstm_fused_kernel<64, false, true>,
                            hipFuncAttributeMaxDynamicSharedMemorySize, LSTM_LDS_BYTES);

  conv_x_kernel<<<2048, 256, 0, stream>>>(x, curA, M * HID, tctr);
  for (int l = 0; l < 3; ++l) {
    const int Fo = (l == 2) ? 64 : 128;
    conv_layer_kernel<<<256, 256, 0, stream>>>(Wih[l], Whh[l], bih[l], bhh[l], Wl[l], Wr[l],
                                               Fo * HID, wihB[l], whhB[l], wlB[l], wrB[l], bsum[l]);
  }

  short* cur = curA;
  short* nxt = curB;
  for (int l = 0; l < 3; ++l) {
    pgemm_kernel<<<784, 512, 0, stream>>>(cur, wihB[l], bsum[l], Pbuf, M, ntiles);
    if (l < 2) {
      lstm_fused_kernel<128, true, false><<<256, 512, LSTM_LDS_BYTES, stream>>>(
          Pbuf, whhB[l], src, cur, wlB[l], wrB[l], bl[l], nxt, nullptr, M, nltiles, tctr + l);
      short* tswap = cur; cur = nxt; nxt = tswap;
    } else {
      lstm_fused_kernel<64, false, true><<<256, 512, LSTM_LDS_BYTES, stream>>>(
          Pbuf, whhB[l], src, cur, wlB[l], wrB[l], bl[l], nullptr, (float*)d_out, M, nltiles, tctr + 2);
    }
  }
}